// Round 1
// baseline (353.149 us; speedup 1.0000x reference)
//
#include <hip/hip_runtime.h>
#include <stdint.h>

#define NTOK 16384
#define HD   2048
#define ID   768
#define TOPK 8

typedef __bf16 bf16x8 __attribute__((ext_vector_type(8)));
typedef float  floatx4 __attribute__((ext_vector_type(4)));
typedef unsigned short ushort8 __attribute__((ext_vector_type(8)));

__device__ __forceinline__ unsigned short f32_to_bf16_rne(float f) {
    union { float f; uint32_t u; } v; v.f = f;
    uint32_t u = v.u;
    u += 0x7FFFu + ((u >> 16) & 1u);   // round-to-nearest-even
    return (unsigned short)(u >> 16);
}

// async global->LDS, 16B per lane; LDS dest must be wave-uniform base (lane*16 implicit)
#define GLD_LDS(gsrc, ldst)                                                              \
    __builtin_amdgcn_global_load_lds(                                                    \
        (const __attribute__((address_space(1))) uint32_t*)(const void*)(gsrc),          \
        (__attribute__((address_space(3))) uint32_t*)(void*)(ldst), 16, 0, 0)

// ---------------- w[k] = sum_j mask[j,k] * rw[k,j] ----------------
__global__ __launch_bounds__(256) void compute_w_kernel(const int* __restrict__ mask,
                                                        const float* __restrict__ rw,
                                                        float* __restrict__ w) {
    int k = blockIdx.x * 256 + threadIdx.x;
    if (k >= NTOK) return;
    float acc = 0.f;
#pragma unroll
    for (int j = 0; j < TOPK; ++j)
        acc += (float)mask[j * NTOK + k] * rw[k * TOPK + j];
    w[k] = acc;
}

// ---------------- fp32 -> bf16 (8 elems/thread) ----------------
__global__ __launch_bounds__(256) void convert_bf16_kernel(const float* __restrict__ src,
                                                           unsigned short* __restrict__ dst,
                                                           int n8) {
    int i = blockIdx.x * 256 + threadIdx.x;
    if (i >= n8) return;
    const float4* s = (const float4*)src;
    float4 a = s[2 * (size_t)i], b = s[2 * (size_t)i + 1];
    ushort8 o;
    o[0] = f32_to_bf16_rne(a.x); o[1] = f32_to_bf16_rne(a.y);
    o[2] = f32_to_bf16_rne(a.z); o[3] = f32_to_bf16_rne(a.w);
    o[4] = f32_to_bf16_rne(b.x); o[5] = f32_to_bf16_rne(b.y);
    o[6] = f32_to_bf16_rne(b.z); o[7] = f32_to_bf16_rne(b.w);
    *(ushort8*)(dst + 8 * (size_t)i) = o;
}

// ---------------- GEMM1: act = silu(A*Gw^T) * (A*Uw^T), bf16 out ----------------
// A [NTOK,HD] bf16, Bg/Bu [ID,HD] bf16 (row-major = B^T form). 128x128 tile, BK=64.
__global__ __launch_bounds__(256) void gemm1_kernel(const unsigned short* __restrict__ A,
                                                    const unsigned short* __restrict__ Bg,
                                                    const unsigned short* __restrict__ Bu,
                                                    unsigned short* __restrict__ act) {
    __shared__ unsigned short As[128 * 64];
    __shared__ unsigned short Bgs[128 * 64];
    __shared__ unsigned short Bus[128 * 64];

    const int tid  = threadIdx.x;
    const int wid  = tid >> 6;
    const int lane = tid & 63;
    const int row0 = blockIdx.y * 128;
    const int col0 = blockIdx.x * 128;

    const int srow = lane >> 3;          // staging: row within 8-row chunk
    const int scol = (lane & 7) * 8;     // staging: k-offset (elems)

    floatx4 zero = {0.f, 0.f, 0.f, 0.f};
    floatx4 accg[4][4], accu[4][4];
#pragma unroll
    for (int m = 0; m < 4; ++m)
#pragma unroll
        for (int n = 0; n < 4; ++n) { accg[m][n] = zero; accu[m][n] = zero; }

    const int wr = wid >> 1, wc = wid & 1;
    const int lrow = lane & 15;
    const int kgrp = (lane >> 4) * 8;

    for (int kt = 0; kt < HD / 64; ++kt) {
        const int k0 = kt * 64;
#pragma unroll
        for (int it = 0; it < 4; ++it) {
            const int chunk = wid * 4 + it;          // 0..15
            const int r = chunk * 8 + srow;          // row in tile
            const size_t goffA = (size_t)(row0 + r) * HD + k0 + scol;
            const size_t goffB = (size_t)(col0 + r) * HD + k0 + scol;
            GLD_LDS(A + goffA, &As[chunk * 512]);
            GLD_LDS(Bg + goffB, &Bgs[chunk * 512]);
            GLD_LDS(Bu + goffB, &Bus[chunk * 512]);
        }
        __syncthreads();
#pragma unroll
        for (int ks = 0; ks < 2; ++ks) {
            const int kk = ks * 32 + kgrp;
            bf16x8 a[4], bg[4], bu[4];
#pragma unroll
            for (int m = 0; m < 4; ++m)
                a[m] = *(const bf16x8*)&As[(wr * 64 + m * 16 + lrow) * 64 + kk];
#pragma unroll
            for (int n = 0; n < 4; ++n) {
                bg[n] = *(const bf16x8*)&Bgs[(wc * 64 + n * 16 + lrow) * 64 + kk];
                bu[n] = *(const bf16x8*)&Bus[(wc * 64 + n * 16 + lrow) * 64 + kk];
            }
#pragma unroll
            for (int m = 0; m < 4; ++m)
#pragma unroll
                for (int n = 0; n < 4; ++n) {
                    accg[m][n] = __builtin_amdgcn_mfma_f32_16x16x32_bf16(a[m], bg[n], accg[m][n], 0, 0, 0);
                    accu[m][n] = __builtin_amdgcn_mfma_f32_16x16x32_bf16(a[m], bu[n], accu[m][n], 0, 0, 0);
                }
        }
        __syncthreads();
    }

    // epilogue: silu(g)*u -> bf16. D frag: col=lane&15, row=(lane>>4)*4+r
#pragma unroll
    for (int m = 0; m < 4; ++m) {
#pragma unroll
        for (int r = 0; r < 4; ++r) {
            const int row = row0 + wr * 64 + m * 16 + (lane >> 4) * 4 + r;
#pragma unroll
            for (int n = 0; n < 4; ++n) {
                const int col = col0 + wc * 64 + n * 16 + lrow;
                float g = accg[m][n][r], u = accu[m][n][r];
                float s = g / (1.f + __expf(-g)) * u;
                act[(size_t)row * ID + col] = f32_to_bf16_rne(s);
            }
        }
    }
}

// ---------------- GEMM2: out = final + w[row] * (act * Dw^T) ----------------
// A [NTOK,ID] bf16, Bd [HD,ID] bf16. 128x128 tile, BK=64, fp32 epilogue.
__global__ __launch_bounds__(256) void gemm2_kernel(const unsigned short* __restrict__ A,
                                                    const unsigned short* __restrict__ Bd,
                                                    const float* __restrict__ fin,
                                                    const float* __restrict__ wtok,
                                                    float* __restrict__ out) {
    __shared__ unsigned short As[128 * 64];
    __shared__ unsigned short Bs[128 * 64];

    const int tid  = threadIdx.x;
    const int wid  = tid >> 6;
    const int lane = tid & 63;
    const int row0 = blockIdx.y * 128;
    const int col0 = blockIdx.x * 128;

    const int srow = lane >> 3;
    const int scol = (lane & 7) * 8;

    floatx4 zero = {0.f, 0.f, 0.f, 0.f};
    floatx4 acc[4][4];
#pragma unroll
    for (int m = 0; m < 4; ++m)
#pragma unroll
        for (int n = 0; n < 4; ++n) acc[m][n] = zero;

    const int wr = wid >> 1, wc = wid & 1;
    const int lrow = lane & 15;
    const int kgrp = (lane >> 4) * 8;

    for (int kt = 0; kt < ID / 64; ++kt) {
        const int k0 = kt * 64;
#pragma unroll
        for (int it = 0; it < 4; ++it) {
            const int chunk = wid * 4 + it;
            const int r = chunk * 8 + srow;
            GLD_LDS(A + (size_t)(row0 + r) * ID + k0 + scol, &As[chunk * 512]);
            GLD_LDS(Bd + (size_t)(col0 + r) * ID + k0 + scol, &Bs[chunk * 512]);
        }
        __syncthreads();
#pragma unroll
        for (int ks = 0; ks < 2; ++ks) {
            const int kk = ks * 32 + kgrp;
            bf16x8 a[4], b[4];
#pragma unroll
            for (int m = 0; m < 4; ++m)
                a[m] = *(const bf16x8*)&As[(wr * 64 + m * 16 + lrow) * 64 + kk];
#pragma unroll
            for (int n = 0; n < 4; ++n)
                b[n] = *(const bf16x8*)&Bs[(wc * 64 + n * 16 + lrow) * 64 + kk];
#pragma unroll
            for (int m = 0; m < 4; ++m)
#pragma unroll
                for (int n = 0; n < 4; ++n)
                    acc[m][n] = __builtin_amdgcn_mfma_f32_16x16x32_bf16(a[m], b[n], acc[m][n], 0, 0, 0);
        }
        __syncthreads();
    }

#pragma unroll
    for (int m = 0; m < 4; ++m) {
#pragma unroll
        for (int r = 0; r < 4; ++r) {
            const int row = row0 + wr * 64 + m * 16 + (lane >> 4) * 4 + r;
            const float wv = wtok[row];
#pragma unroll
            for (int n = 0; n < 4; ++n) {
                const int col = col0 + wc * 64 + n * 16 + lrow;
                out[(size_t)row * HD + col] = fin[(size_t)row * HD + col] + wv * acc[m][n][r];
            }
        }
    }
}

extern "C" void kernel_launch(void* const* d_in, const int* in_sizes, int n_in,
                              void* d_out, int out_size, void* d_ws, size_t ws_size,
                              hipStream_t stream) {
    const float* hs   = (const float*)d_in[0];
    const int*   mask = (const int*)d_in[1];
    const float* rw   = (const float*)d_in[2];
    const float* fin  = (const float*)d_in[3];
    const float* gw   = (const float*)d_in[4];
    const float* uw   = (const float*)d_in[5];
    const float* dw   = (const float*)d_in[6];
    float* out = (float*)d_out;

    char* ws = (char*)d_ws;
    unsigned short* hs_b   = (unsigned short*)ws; ws += (size_t)NTOK * HD * 2;
    unsigned short* gate_b = (unsigned short*)ws; ws += (size_t)ID * HD * 2;
    unsigned short* up_b   = (unsigned short*)ws; ws += (size_t)ID * HD * 2;
    unsigned short* down_b = (unsigned short*)ws; ws += (size_t)HD * ID * 2;
    unsigned short* act_b  = (unsigned short*)ws; ws += (size_t)NTOK * ID * 2;
    float* wtok = (float*)ws;

    compute_w_kernel<<<NTOK / 256, 256, 0, stream>>>(mask, rw, wtok);

    convert_bf16_kernel<<<(NTOK * HD / 8) / 256, 256, 0, stream>>>(hs, hs_b, NTOK * HD / 8);
    convert_bf16_kernel<<<(ID * HD / 8) / 256, 256, 0, stream>>>(gw, gate_b, ID * HD / 8);
    convert_bf16_kernel<<<(ID * HD / 8) / 256, 256, 0, stream>>>(uw, up_b, ID * HD / 8);
    convert_bf16_kernel<<<(HD * ID / 8) / 256, 256, 0, stream>>>(dw, down_b, HD * ID / 8);

    gemm1_kernel<<<dim3(ID / 128, NTOK / 128), 256, 0, stream>>>(hs_b, gate_b, up_b, act_b);
    gemm2_kernel<<<dim3(HD / 128, NTOK / 128), 256, 0, stream>>>(act_b, down_b, fin, wtok, out);
}